// Round 5
// baseline (444.451 us; speedup 1.0000x reference)
//
#include <hip/hip_runtime.h>

#define SEQ   512
#define BATCH 256
#define DIN   128
#define HID   256

__device__ __forceinline__ float dot4(float4 a, float4 b) {
    return fmaf(a.x, b.x, fmaf(a.y, b.y, fmaf(a.z, b.z, a.w * b.w)));
}
__device__ __forceinline__ float tanh_(float x) {      // round-2 bitwise
    float ax = fabsf(x);
    float e  = __expf(2.0f * ax);
    float r  = 1.0f - 2.0f / (e + 1.0f);
    return copysignf(r, x);
}
template <int CTRL>
__device__ __forceinline__ float dppf(float v) {
    return __int_as_float(__builtin_amdgcn_mov_dpp(__float_as_int(v), CTRL, 0xF, 0xF, false));
}
template <int CTRL>
__device__ __forceinline__ float4 dpp4(float4 v) {
    return make_float4(dppf<CTRL>(v.x), dppf<CTRL>(v.y), dppf<CTRL>(v.z), dppf<CTRL>(v.w));
}
__device__ __forceinline__ float swap16_sum(float v) {
    float a = v, b;
    asm("v_mov_b32 %1, %0\n\tv_permlane16_swap_b32 %0, %1" : "+v"(a), "=&v"(b));
    return a + b;
}
__device__ __forceinline__ float swap32_sum(float v) {
    float a = v, b;
    asm("v_mov_b32 %1, %0\n\tv_permlane32_swap_b32 %0, %1" : "+v"(a), "=&v"(b));
    return a + b;
}
__device__ __forceinline__ float rdlanef(float v, int lane) {
    return __int_as_float(__builtin_amdgcn_readlane(__float_as_int(v), lane));
}

// ---------------------------------------------------------------------------
// Kernel 1: pre[s,b,p] = b_lin[p] + theta[p] + sum_d w_lin[p,d] * x[s,b,d]
// (bitwise-identical to round 2)
// ---------------------------------------------------------------------------
__global__ __launch_bounds__(256, 4) void pre_gemm(
    const float* __restrict__ x,      // (S,B,D)
    const float* __restrict__ w_lin,  // (16,384) x-part = [0:128)
    const float* __restrict__ b_lin,  // (16,)
    const float* __restrict__ theta,  // (16,)
    float* pre, int pstride)
{
    __shared__ float wlds[16 * 132];
    const int t = threadIdx.x;
    for (int i = t; i < 16 * 128; i += 256) {
        int pp = i >> 7, dd = i & 127;
        wlds[pp * 132 + dd] = w_lin[pp * 384 + dd];
    }
    __syncthreads();
    const int s = blockIdx.x >> 4;
    const int b = ((blockIdx.x & 15) << 4) + (t >> 4);
    const int p = t & 15;
    const float* xr = x + ((size_t)s * BATCH + b) * DIN;
    const float* wr = &wlds[p * 132];
    float acc = b_lin[p] + theta[p];
    #pragma unroll 8
    for (int d = 0; d < 32; ++d)
        acc += dot4(*(const float4*)(xr + d * 4), *(const float4*)(wr + d * 4));
    pre[((size_t)s * BATCH + b) * pstride + p] = acc;
}

// ---------------------------------------------------------------------------
// Kernel 2: recurrence — ONE WAVE per batch element, no LDS, no barriers,
// arithmetic replicated BITWISE from the round-2 passing kernel:
//  - per-lane partial uses the sig(Q)-permuted add order (round 2's swizzle)
//  - acts taken from canonical lanes 0..3 (Q=0 tree order) via v_readlane,
//    so all lanes consume ONE act rounding (round 2's LDS broadcast semantics)
//  - ez groupings (0.99*u)*v and tanh_/sigmoid formulas exactly as round 2
// ---------------------------------------------------------------------------
__global__ __launch_bounds__(64, 1) void qlstm_rec(
    const float* __restrict__ w_lin,  // (16, 384), hx part = [128:384)
    const float* __restrict__ w_map,  // (4, 256, 4)
    const float* __restrict__ b_map,  // (4, 256)
    const float* pre, int pstride,    // may alias out (no restrict!)
    float* out)
{
    const int b = blockIdx.x;
    const int l = threadIdx.x;        // 0..63
    const int a = l & 3;              // owned gate
    const int Q = l >> 2;             // quad; partial covers hx[16Q..16Q+15]
    const bool sg1 = (Q >> 1) & 1;    // sig bit 0   (sig = (Q>>1)&3)
    const bool sg2 = (Q >> 2) & 1;    // sig bit 1
    const bool isT = (a == 2);        // tanh gate

    // phase-1 weights: wh4[q][c] = Wh[p=4a+q][h = 16Q+4c .. +3]
    float4 wh4[4][4];
    #pragma unroll
    for (int q = 0; q < 4; ++q)
        #pragma unroll
        for (int c = 0; c < 4; ++c)
            wh4[q][c] = *(const float4*)(w_lin + (4*a + q) * 384 + 128 + 16*Q + 4*c);

    // phase-2 weights/biases for own 4 h values (h = 4l+m)
    float4 wm[4][4];
    float  bmv[4][4];
    #pragma unroll
    for (int g2 = 0; g2 < 4; ++g2) {
        #pragma unroll
        for (int m = 0; m < 4; ++m)
            wm[g2][m] = *(const float4*)(w_map + ((size_t)(g2 * 256 + 4*l + m)) * 4);
        float4 bq = *(const float4*)(b_map + g2 * 256 + 4*l);
        bmv[g2][0] = bq.x; bmv[g2][1] = bq.y; bmv[g2][2] = bq.z; bmv[g2][3] = bq.w;
    }

    const float nm = isT ? 2.0f : 1.0f;

    const float* pb = pre + (size_t)b * pstride + 4*a;
    const size_t sstride = (size_t)BATCH * pstride;
    float4 px0 = *(const float4*)(pb);
    float4 px1 = *(const float4*)(pb + sstride);

    float4 hxv = make_float4(0.f, 0.f, 0.f, 0.f);
    float  cxa[4] = {0.f, 0.f, 0.f, 0.f};

    float* outp   = out + (size_t)b * HID + 4*l;
    float* out_hx = out + (size_t)SEQ * BATCH * HID;
    float* out_cx = out_hx + BATCH * HID;

    for (int s = 0; s < SEQ; ++s) {
        const float4 pcur = px0;
        px0 = px1;
        const int s2 = (s + 2 < SEQ) ? (s + 2) : (SEQ - 1);
        px1 = *(const float4*)(pb + (size_t)s2 * sstride);

        // ---- phase 1: quad-allgather hx (exact f32 values) ----------------
        const float4 h0 = dpp4<0x00>(hxv);
        const float4 h1 = dpp4<0x55>(hxv);
        const float4 h2 = dpp4<0xAA>(hxv);
        const float4 h3 = dpp4<0xFF>(hxv);

        // partial dots with round-2's sig-permuted add order, then the same
        // ror4/ror8/swap16/swap32 tree (canonical value lands at lanes 0..3)
        float pq[4];
        #pragma unroll
        for (int q = 0; q < 4; ++q) {
            const float d0 = dot4(wh4[q][0], h0);
            const float d1 = dot4(wh4[q][1], h1);
            const float d2 = dot4(wh4[q][2], h2);
            const float d3 = dot4(wh4[q][3], h3);
            const float A01 = d0 + d1;
            const float A23 = d2 + d3;
            // ((b_sig + b_{1^sig}) + b_{2^sig}) + b_{3^sig}
            const float t1 = sg2 ? A23 : A01;
            const float u  = sg2 ? (sg1 ? d1 : d0) : (sg1 ? d3 : d2);
            const float w  = sg2 ? (sg1 ? d0 : d1) : (sg1 ? d2 : d3);
            float v = (t1 + u) + w;
            v += dppf<0x124>(v);     // += partial(Q+1)
            v += dppf<0x128>(v);     // += partial(Q+2)
            v  = swap16_sum(v);      // += Q^4 subtree
            v  = swap32_sum(v);      // += Q^8 subtree
            pq[q] = v;
        }

        // ---- quantum layer (round-2 bitwise groupings) --------------------
        const float A0 = __cosf(pq[0] + pcur.x);
        const float A1 = __cosf(pq[1] + pcur.y);
        const float A2 = __cosf(pq[2] + pcur.z);
        const float A3 = __cosf(pq[3] + pcur.w);

        const float s01 = A0 * A1;          // == C1*C0 bitwise
        const float s23 = A2 * A3;          // == C3*C2 bitwise
        const float ezv[4] = {
            (0.99f * A1)  * s23,            // q=0: (0.99*C1)*(C2*C3)
            (0.99f * s01) * 1.0f,           // q=1: (0.99*(C1*C0))*1
            (0.99f * A2)  * s01,            // q=2: (0.99*C2)*(C0*C1)
            (0.99f * s23) * s01             // q=3: (0.99*(C3*C2))*(C1*C0)
        };

        // act: round 2's sigmoid_/tanh_ sharing one expf + one division
        float act[4];
        #pragma unroll
        for (int q = 0; q < 4; ++q) {
            const float z   = ezv[q];
            const float arg = isT ? 2.0f * fabsf(z) : -z;
            const float E   = __expf(arg);
            const float dd  = nm / (E + 1.0f);
            act[q] = isT ? copysignf(1.0f - dd, z) : dd;
        }

        // ---- canonical acts from lanes 0..3 (uniform, SGPR broadcast) -----
        const float4 AR0 = make_float4(rdlanef(act[0],0), rdlanef(act[1],0), rdlanef(act[2],0), rdlanef(act[3],0));
        const float4 AR1 = make_float4(rdlanef(act[0],1), rdlanef(act[1],1), rdlanef(act[2],1), rdlanef(act[3],1));
        const float4 AR2 = make_float4(rdlanef(act[0],2), rdlanef(act[1],2), rdlanef(act[2],2), rdlanef(act[3],2));
        const float4 AR3 = make_float4(rdlanef(act[0],3), rdlanef(act[1],3), rdlanef(act[2],3), rdlanef(act[3],3));

        // ---- phase 2: gate matvec + cell update (round-2 bitwise) ---------
        float hxa[4];
        #pragma unroll
        for (int m = 0; m < 4; ++m) {
            const float fv = bmv[0][m] + dot4(wm[0][m], AR0);
            const float iv = bmv[1][m] + dot4(wm[1][m], AR1);
            const float gv = bmv[2][m] + dot4(wm[2][m], AR2);
            const float ov = bmv[3][m] + dot4(wm[3][m], AR3);
            cxa[m] = fmaf(fv, cxa[m], iv * gv);
            hxa[m] = ov * tanh_(cxa[m]);
        }
        hxv = make_float4(hxa[0], hxa[1], hxa[2], hxa[3]);

        *(float4*)outp = hxv;
        outp += (size_t)BATCH * HID;
    }

    *(float4*)(out_hx + (size_t)b * HID + 4*l) = hxv;
    *(float4*)(out_cx + (size_t)b * HID + 4*l) = make_float4(cxa[0], cxa[1], cxa[2], cxa[3]);
}

extern "C" void kernel_launch(void* const* d_in, const int* in_sizes, int n_in,
                              void* d_out, int out_size, void* d_ws, size_t ws_size,
                              hipStream_t stream) {
    const float* x     = (const float*)d_in[0];
    const float* w_lin = (const float*)d_in[1];
    const float* b_lin = (const float*)d_in[2];
    const float* w_map = (const float*)d_in[3];
    const float* b_map = (const float*)d_in[4];
    const float* theta = (const float*)d_in[5];
    float* out = (float*)d_out;

    const size_t pre_bytes = (size_t)SEQ * BATCH * 16 * sizeof(float);
    float* pre;
    int pstride;
    if (ws_size >= pre_bytes) {
        pre = (float*)d_ws;
        pstride = 16;
    } else {
        pre = out;                        // row s overwritten only at end of step s;
        pstride = HID;                    // reads run 2 steps ahead of the overwrite
    }

    pre_gemm<<<dim3(SEQ * 16), dim3(256), 0, stream>>>(x, w_lin, b_lin, theta, pre, pstride);
    qlstm_rec<<<dim3(BATCH), dim3(64), 0, stream>>>(w_lin, w_map, b_map, pre, pstride, out);
}